// Round 6
// baseline (453.157 us; speedup 1.0000x reference)
//
#include <hip/hip_runtime.h>
#include <hip/hip_bf16.h>

// Problem constants
#define NB_  16
#define NPTS 8192
#define NG   256
#define NP   (NB_*NPTS)   // 131072 points

// Output segment offsets (floats)
#define OFF_CENT 0
#define OFF_OUT  12288
#define OFF_PI   1060864
#define OFF_LAB  1454080

typedef unsigned short u16;
typedef __attribute__((ext_vector_type(8))) short bf16x8;
typedef __attribute__((ext_vector_type(4))) float f32x4;

// Workspace layout (bytes)
static constexpr size_t WS_SUMS  = 0;                                // B*G*4 f32 = 64KB
static constexpr size_t WS_A1    = 65536;                            // P*128 bf16 = 32MB (sorted)
static constexpr size_t WS_H     = WS_A1   + (size_t)NP*128*2;       // P*256 bf16 = 64MB (sorted)
static constexpr size_t WS_POOLU = WS_H    + (size_t)NP*256*2;       // B*G*256 u32 = 4MB
static constexpr size_t WS_PBF   = WS_POOLU + (size_t)NB_*NG*256*4;  // B*G*256 bf16 = 2MB
static constexpr size_t WS_OUTU  = WS_PBF   + (size_t)NB_*NG*256*2;  // B*G*256 u32 = 4MB
static constexpr size_t WS_WT1   = WS_OUTU  + (size_t)NB_*NG*256*4;  // 256x128 bf16
static constexpr size_t WS_WT2A  = WS_WT1   + (size_t)256*128*2;     // 512x512 bf16
static constexpr size_t WS_WT2B  = WS_WT2A  + (size_t)512*512*2;     // 256x512 bf16
static constexpr size_t WS_PREP  = WS_WT2B  + (size_t)256*512*2;     // 4096x512 f32 = 8MB
static constexpr size_t WS_OFFS  = WS_PREP  + (size_t)NB_*NG*512*4;  // 4096 i32
static constexpr size_t WS_CUR   = WS_OFFS  + (size_t)NB_*NG*4;      // 4096 i32
static constexpr size_t WS_SPOS  = WS_CUR   + (size_t)NB_*NG*4;      // NP i32 = 512KB
static constexpr size_t WS_GLAB  = WS_SPOS  + (size_t)NP*4;          // NP i32 = 512KB
static constexpr size_t WS_NEED  = WS_GLAB  + (size_t)NP*4;          // ~116 MB

// Order-preserving float<->uint mapping for atomicMax-based segment max
__device__ __forceinline__ unsigned mapf(float x){
  unsigned u = __float_as_uint(x);
  return (u & 0x80000000u) ? ~u : (u | 0x80000000u);
}
__device__ __forceinline__ float unmapf(unsigned u){
  return (u & 0x80000000u) ? __uint_as_float(u & 0x7FFFFFFFu) : __uint_as_float(~u);
}
#define MAP_NEG_INF 0x007FFFFFu   // mapf(-inf)

__device__ __forceinline__ u16 f2bf_bits(float f){
  __hip_bfloat16 h = __float2bfloat16(f);
  union { __hip_bfloat16 h; u16 s; } u; u.h = h; return u.s;
}
__device__ __forceinline__ float bf_bits2f(u16 s){
  return __uint_as_float(((unsigned)s) << 16);
}

// async global->LDS, 16B per lane. LDS dest must be wave-uniform base (lane*16 added by HW).
__device__ __forceinline__ void gload16(const void* g, void* l){
  __builtin_amdgcn_global_load_lds((const __attribute__((address_space(1))) void*)g,
                                   (__attribute__((address_space(3))) void*)l, 16, 0, 0);
}

// ---------------- init: zero sums+cursor, -inf the max buffers ----------------
__global__ void k_init(float* __restrict__ sums, int* __restrict__ cursor,
                       unsigned* __restrict__ pool_u, unsigned* __restrict__ out_u){
  int i = blockIdx.x*blockDim.x + threadIdx.x;
  if (i < NB_*NG*4) sums[i] = 0.f;
  if (i < NB_*NG) cursor[i] = 0;
  if (i < NB_*NG*256){ pool_u[i] = MAP_NEG_INF; out_u[i] = MAP_NEG_INF; }
}

// ---------------- weight transpose+bf16: dst[n*K+k] = bf16(src[k*N+n]) ----------------
__global__ void k_wt(const float* __restrict__ src, u16* __restrict__ dst, int K, int N){
  int i = blockIdx.x*blockDim.x + threadIdx.x;
  if (i >= K*N) return;
  int n = i / K, k = i - n*K;
  dst[i] = f2bf_bits(src[(size_t)k*N + n]);
}

// ---------------- per-point pass 1: segment sums + labels-as-float ----------------
__global__ void k_points(const float* __restrict__ xyz, const int* __restrict__ labels,
                         float* __restrict__ sums, float* __restrict__ outLab){
  int p = blockIdx.x*blockDim.x + threadIdx.x;
  if (p >= NP) return;
  int b = p / NPTS;
  int g = labels[p];
  float x = xyz[p*3+0], y = xyz[p*3+1], z = xyz[p*3+2];
  float* s = sums + (size_t)(b*NG + g)*4;
  atomicAdd(s+0, x); atomicAdd(s+1, y); atomicAdd(s+2, z); atomicAdd(s+3, 1.f);
  outLab[p] = (float)g;
}

// ---------------- centroids ----------------
__global__ void k_cent(const float* __restrict__ sums, float* __restrict__ cent_out){
  int i = blockIdx.x*blockDim.x + threadIdx.x;   // b*G+g
  if (i >= NB_*NG) return;
  const float* s = sums + (size_t)i*4;
  float c = fmaxf(s[3], 1.f);
  cent_out[i*3+0] = s[0]/c;
  cent_out[i*3+1] = s[1]/c;
  cent_out[i*3+2] = s[2]/c;
}

// ---------------- exclusive scan of counts per batch -> offs ----------------
__global__ void k_scan(const float* __restrict__ sums, int* __restrict__ offs){
  __shared__ int sc[256];
  int b = blockIdx.x, g = threadIdx.x;
  int c = (int)(sums[(size_t)(b*NG+g)*4+3] + 0.5f);
  sc[g] = c;
  __syncthreads();
  for (int d = 1; d < 256; d <<= 1){
    int t = (g >= d) ? sc[g-d] : 0;
    __syncthreads();
    sc[g] += t;
    __syncthreads();
  }
  offs[b*NG+g] = b*NPTS + sc[g] - c;   // exclusive
}

// ---------------- scatter: sorted position per point; sorted labels ----------------
__global__ void k_scatter(const int* __restrict__ labels, const int* __restrict__ offs,
                          int* __restrict__ cursor, int* __restrict__ sortpos,
                          int* __restrict__ glab){
  int p = blockIdx.x*blockDim.x + threadIdx.x;
  if (p >= NP) return;
  int b = p / NPTS, g = labels[p];
  int pos = offs[b*NG+g] + atomicAdd(&cursor[b*NG+g], 1);
  sortpos[p] = pos;
  glab[pos] = g;
}

// ---------------- MLP1 front: rel@w1a+b1a -> LN -> ReLU -> a1 (bf16, SORTED), also p_i ----
__global__ __launch_bounds__(256) void k_mlp1(
    const float* __restrict__ xyz, const int* __restrict__ labels,
    const int* __restrict__ sortpos, const float* __restrict__ cent,
    const float* __restrict__ w1a, const float* __restrict__ b1a,
    const float* __restrict__ g1, const float* __restrict__ beta1,
    u16* __restrict__ a1, float* __restrict__ pi_out)
{
  int wave = (int)((blockIdx.x*blockDim.x + threadIdx.x) >> 6);
  int lane = threadIdx.x & 63;
  int p = wave;
  if (p >= NP) return;
  int b = p / NPTS;
  int g = labels[p];
  const float* cb = cent + (size_t)(b*NG+g)*3;
  float c0 = cb[0], c1 = cb[1], c2 = cb[2];
  float r0 = xyz[p*3+0]-c0, r1 = xyz[p*3+1]-c1, r2 = xyz[p*3+2]-c2;
  if (lane < 3) pi_out[(size_t)p*3+lane] = (lane==0?c0:(lane==1?c1:c2));
  int j = lane*2;
  float2 wa0 = *(const float2*)(w1a + 0*128 + j);
  float2 wa1 = *(const float2*)(w1a + 1*128 + j);
  float2 wa2 = *(const float2*)(w1a + 2*128 + j);
  float2 bb  = *(const float2*)(b1a + j);
  float t0 = bb.x + r0*wa0.x + r1*wa1.x + r2*wa2.x;
  float t1 = bb.y + r0*wa0.y + r1*wa1.y + r2*wa2.y;
  float s = t0+t1, sq = t0*t0 + t1*t1;
  #pragma unroll
  for (int m = 32; m; m >>= 1){ s += __shfl_xor(s, m); sq += __shfl_xor(sq, m); }
  float mu  = s * (1.f/128.f);
  float var = sq * (1.f/128.f) - mu*mu;
  float inv = rsqrtf(var + 1e-5f);
  float2 gg = *(const float2*)(g1 + j), be = *(const float2*)(beta1 + j);
  float a0 = fmaxf((t0-mu)*inv*gg.x + be.x, 0.f);
  float a1v = fmaxf((t1-mu)*inv*gg.y + be.y, 0.f);
  unsigned pk = ((unsigned)f2bf_bits(a1v) << 16) | f2bf_bits(a0);
  int sp = sortpos[p];
  *reinterpret_cast<unsigned*>(a1 + (size_t)sp*128 + j) = pk;
}

// ---------------- MFMA bf16 GEMM (generic): C[M][Nc] = A@B + bias ----------------
// Rows are SORTED-by-label order for EPI 0; labels = glab (sorted labels).
// EPI 0: bf16 store + run-dedup atomicMax(maxbuf);  EPI 3: f32 store (Cf).
template<int EPI>
__global__ __launch_bounds__(256)
void mgemm(const u16* __restrict__ A, int lda, int K,
           const u16* __restrict__ BT, int ldb, int kofs,
           const float* __restrict__ bias,
           const int* __restrict__ labels,
           u16* __restrict__ Cst, float* __restrict__ Cf, int ldc, int Nc,
           unsigned* __restrict__ maxbuf)
{
  __shared__ alignas(16) u16 As[128*32];
  __shared__ alignas(16) u16 Bs[128*32];
  int NBk = Nc >> 7;
  int bm = blockIdx.x / NBk, bn = blockIdx.x % NBk;
  int m0 = bm << 7, n0 = bn << 7;
  int tid = threadIdx.x;
  int lane = tid & 63, w = tid >> 6;
  int wr = w >> 1, wc = w & 1;
  int l15 = lane & 15, l4 = lane >> 4;
  int r0 = tid >> 2;
  int ks = (tid & 3) << 3;
  u16* asd0 = As + (size_t)(w*64)*8;
  u16* asd1 = As + (size_t)(256 + w*64)*8;
  u16* bsd0 = Bs + (size_t)(w*64)*8;
  u16* bsd1 = Bs + (size_t)(256 + w*64)*8;
  f32x4 acc[4][4];
  #pragma unroll
  for (int i = 0; i < 4; ++i)
    #pragma unroll
    for (int jj = 0; jj < 4; ++jj)
      #pragma unroll
      for (int e = 0; e < 4; ++e) acc[i][jj][e] = 0.f;

  for (int k0 = 0; k0 < K; k0 += 32){
    gload16(A + (size_t)(m0 + r0)*lda + k0 + ks, asd0);
    gload16(A + (size_t)(m0 + r0 + 64)*lda + k0 + ks, asd1);
    gload16(BT + (size_t)(n0 + r0)*ldb + kofs + k0 + ks, bsd0);
    gload16(BT + (size_t)(n0 + r0 + 64)*ldb + kofs + k0 + ks, bsd1);
    __syncthreads();
    bf16x8 af[4], bfr[4];
    #pragma unroll
    for (int i = 0; i < 4; ++i){
      af[i]  = *(const bf16x8*)&As[(size_t)(wr*64 + i*16 + l15)*32 + l4*8];
      bfr[i] = *(const bf16x8*)&Bs[(size_t)(wc*64 + i*16 + l15)*32 + l4*8];
    }
    #pragma unroll
    for (int i = 0; i < 4; ++i)
      #pragma unroll
      for (int jj = 0; jj < 4; ++jj)
        acc[i][jj] = __builtin_amdgcn_mfma_f32_16x16x32_bf16(af[i], bfr[jj], acc[i][jj], 0, 0, 0);
    __syncthreads();
  }

  float bi[4];
  #pragma unroll
  for (int jj = 0; jj < 4; ++jj) bi[jj] = bias[n0 + wc*64 + jj*16 + l15];
  #pragma unroll
  for (int i = 0; i < 4; ++i){
    int g_[4];
    if (EPI == 0){
      #pragma unroll
      for (int r = 0; r < 4; ++r){
        int m = m0 + wr*64 + i*16 + l4*4 + r;
        g_[r] = (m/NPTS)*NG + labels[m];
      }
    }
    #pragma unroll
    for (int jj = 0; jj < 4; ++jj){
      int n = n0 + wc*64 + jj*16 + l15;
      int cur = -1; float mx = 0.f;
      #pragma unroll
      for (int r = 0; r < 4; ++r){
        int m = m0 + wr*64 + i*16 + l4*4 + r;
        float v = acc[i][jj][r] + bi[jj];
        if (EPI == 0){
          Cst[(size_t)m*ldc + n] = f2bf_bits(v);
          if (g_[r] != cur){
            if (cur >= 0) atomicMax(maxbuf + ((size_t)cur << 8) + n, mapf(mx));
            cur = g_[r]; mx = v;
          } else mx = fmaxf(mx, v);
        }
        if (EPI == 3) Cf[(size_t)m*ldc + n] = v;
      }
      if (EPI == 0) atomicMax(maxbuf + ((size_t)cur << 8) + n, mapf(mx));
    }
  }
}

// ---------------- pooled finalize: unmap, -inf -> 0, to bf16 ----------------
__global__ void k_poolfin(const unsigned* __restrict__ pu, u16* __restrict__ pbf){
  int i = blockIdx.x*blockDim.x + threadIdx.x;
  if (i >= NB_*NG*256) return;
  float v = unmapf(pu[i]);
  pbf[i] = f2bf_bits((v > -3.0e38f) ? v : 0.f);
}

// ---------------- fused: u = h@W2a_bot + prep[gather] ; LN+ReLU ; v = u@w2b ; segmax ----
// Rows in sorted-by-label order (h sorted, glab sorted labels).
// 512 threads = 8 waves; M-tile 64 (grid NP/64); LDS 80KB -> 2 blocks/CU.
__global__ __launch_bounds__(512, 4)
void fused2(const u16* __restrict__ h, const u16* __restrict__ wt2a,
            const u16* __restrict__ wt2b, const float* __restrict__ prepf,
            const float* __restrict__ b2b, const float* __restrict__ g2,
            const float* __restrict__ beta2, const int* __restrict__ glab,
            unsigned* __restrict__ out_u)
{
  __shared__ alignas(16) char smem[81920];
  float* ssum = (float*)(smem + 65536);        // [64] f32 (aliases phase-2 B tile)
  float* ssq  = (float*)(smem + 65536 + 256);  // [64] f32
  int tid = threadIdx.x;
  int w = tid >> 6, lane = tid & 63;
  int l15 = lane & 15, l4 = lane >> 4;
  int m0 = blockIdx.x << 6;
  int srow = lane >> 2, skseg = (lane & 3) << 3;
  if (tid < 64){ ssum[tid] = 0.f; ssq[tid] = 0.f; }

  f32x4 acc[4][4];
  #pragma unroll
  for (int i = 0; i < 4; ++i)
    #pragma unroll
    for (int j = 0; j < 4; ++j)
      #pragma unroll
      for (int e = 0; e < 4; ++e) acc[i][j][e] = 0.f;

  // ---- phase 1: acc = h_tile @ W2a_bot ----
  for (int k0 = 0; k0 < 256; k0 += 32){
    if (w < 4)
      gload16(h + (size_t)(m0 + (w<<4) + srow)*256 + k0 + skseg, smem + (w<<10));
    #pragma unroll
    for (int q = 0; q < 4; ++q){
      int n = (w<<6) + (q<<4) + srow;
      gload16(wt2a + (size_t)n*512 + 256 + k0 + skseg,
              smem + 4096 + (((w<<6) + (q<<4)) << 6));
    }
    __syncthreads();
    bf16x8 af[4], bf[4];
    #pragma unroll
    for (int i = 0; i < 4; ++i)
      af[i] = *(const bf16x8*)(smem + ((((i<<4)+l15)) << 6) + (l4<<4));
    #pragma unroll
    for (int j = 0; j < 4; ++j)
      bf[j] = *(const bf16x8*)(smem + 4096 + (((w<<6)+(j<<4)+l15) << 6) + (l4<<4));
    #pragma unroll
    for (int i = 0; i < 4; ++i)
      #pragma unroll
      for (int j = 0; j < 4; ++j)
        acc[i][j] = __builtin_amdgcn_mfma_f32_16x16x32_bf16(af[i], bf[j], acc[i][j], 0, 0, 0);
    __syncthreads();
  }

  // ---- phase 1.5: + prep gather, LayerNorm + ReLU, write u to LDS (swizzled bf16) ----
  int gb = (m0 / NPTS) * NG;
  int grp[4][4];
  #pragma unroll
  for (int i = 0; i < 4; ++i)
    #pragma unroll
    for (int r = 0; r < 4; ++r)
      grp[i][r] = gb + glab[m0 + (i<<4) + (l4<<2) + r];
  #pragma unroll
  for (int i = 0; i < 4; ++i)
    #pragma unroll
    for (int j = 0; j < 4; ++j){
      int n = (w<<6) + (j<<4) + l15;
      #pragma unroll
      for (int r = 0; r < 4; ++r)
        acc[i][j][r] += prepf[((size_t)grp[i][r] << 9) + n];
    }
  #pragma unroll
  for (int i = 0; i < 4; ++i)
    #pragma unroll
    for (int r = 0; r < 4; ++r){
      float s = 0.f, q = 0.f;
      #pragma unroll
      for (int j = 0; j < 4; ++j){ float v = acc[i][j][r]; s += v; q += v*v; }
      #pragma unroll
      for (int mk = 1; mk < 16; mk <<= 1){ s += __shfl_xor(s, mk); q += __shfl_xor(q, mk); }
      if (l15 == 0){
        int row = (i<<4) + (l4<<2) + r;
        atomicAdd(&ssum[row], s);
        atomicAdd(&ssq[row], q);
      }
    }
  __syncthreads();
  if (tid < 64){
    float mu = ssum[tid] * (1.f/512.f);
    float var = ssq[tid] * (1.f/512.f) - mu*mu;
    ssum[tid] = mu;
    ssq[tid] = rsqrtf(var + 1e-5f);
  }
  __syncthreads();
  float gcol[4], bcol[4];
  #pragma unroll
  for (int j = 0; j < 4; ++j){
    int n = (w<<6) + (j<<4) + l15;
    gcol[j] = g2[n]; bcol[j] = beta2[n];
  }
  #pragma unroll
  for (int i = 0; i < 4; ++i)
    #pragma unroll
    for (int r = 0; r < 4; ++r){
      int row = (i<<4) + (l4<<2) + r;
      float mu = ssum[row], inv = ssq[row];
      #pragma unroll
      for (int j = 0; j < 4; ++j){
        int n = (w<<6) + (j<<4) + l15;
        float v = fmaxf((acc[i][j][r] - mu)*inv*gcol[j] + bcol[j], 0.f);
        int byo = (row << 10) + (n << 1);
        byo ^= (row & 7) << 4;
        *(u16*)(smem + byo) = f2bf_bits(v);
      }
    }
  __syncthreads();

  // ---- phase 2: v = u_lds @ w2b ; run-dedup atomicMax segmax ----
  f32x4 acc2[4][2];
  #pragma unroll
  for (int i = 0; i < 4; ++i)
    #pragma unroll
    for (int j = 0; j < 2; ++j)
      #pragma unroll
      for (int e = 0; e < 4; ++e) acc2[i][j][e] = 0.f;

  for (int k0 = 0; k0 < 512; k0 += 32){
    #pragma unroll
    for (int q = 0; q < 2; ++q){
      int n = (w<<5) + (q<<4) + srow;
      gload16(wt2b + (size_t)n*512 + k0 + skseg,
              smem + 65536 + (((w<<5) + (q<<4)) << 6));
    }
    __syncthreads();
    bf16x8 af2[4], bf2[2];
    #pragma unroll
    for (int i = 0; i < 4; ++i){
      int row = (i<<4) + l15;
      int byo = (row << 10) + ((k0 + (l4<<3)) << 1);
      byo ^= (row & 7) << 4;
      af2[i] = *(const bf16x8*)(smem + byo);
    }
    #pragma unroll
    for (int j = 0; j < 2; ++j)
      bf2[j] = *(const bf16x8*)(smem + 65536 + (((w<<5)+(j<<4)+l15) << 6) + (l4<<4));
    #pragma unroll
    for (int i = 0; i < 4; ++i)
      #pragma unroll
      for (int j = 0; j < 2; ++j)
        acc2[i][j] = __builtin_amdgcn_mfma_f32_16x16x32_bf16(af2[i], bf2[j], acc2[i][j], 0, 0, 0);
    __syncthreads();
  }

  float bb0 = b2b[(w<<5) + l15], bb1 = b2b[(w<<5) + 16 + l15];
  #pragma unroll
  for (int i = 0; i < 4; ++i){
    #pragma unroll
    for (int j = 0; j < 2; ++j){
      int n = (w<<5) + (j<<4) + l15;
      float bbj = j ? bb1 : bb0;
      int cur = -1; float mx = 0.f;
      #pragma unroll
      for (int r = 0; r < 4; ++r){
        float v = acc2[i][j][r] + bbj;
        if (grp[i][r] != cur){
          if (cur >= 0) atomicMax(out_u + (((unsigned)cur) << 8) + n, mapf(mx));
          cur = grp[i][r]; mx = v;
        } else mx = fmaxf(mx, v);
      }
      atomicMax(out_u + (((unsigned)cur) << 8) + n, mapf(mx));
    }
  }
}

// ---------------- out finalize ----------------
__global__ void k_outfin(const unsigned* __restrict__ ou, float* __restrict__ dst){
  int i = blockIdx.x*blockDim.x + threadIdx.x;
  if (i >= NB_*NG*256) return;
  float v = unmapf(ou[i]);
  dst[i] = (v > -3.0e38f) ? v : 0.f;
}

// ---------------- ws-too-small signal ----------------
__global__ void k_sig(float* __restrict__ out, float val){
  int i = blockIdx.x*blockDim.x + threadIdx.x;
  if (i < 256) out[i] = val;
}

extern "C" void kernel_launch(void* const* d_in, const int* in_sizes, int n_in,
                              void* d_out, int out_size, void* d_ws, size_t ws_size,
                              hipStream_t stream) {
  const float* xyz    = (const float*)d_in[0];
  const int*   labels = (const int*)  d_in[1];
  const float* w1a    = (const float*)d_in[2];
  const float* b1a    = (const float*)d_in[3];
  const float* g1     = (const float*)d_in[4];
  const float* beta1  = (const float*)d_in[5];
  const float* w1b    = (const float*)d_in[6];
  const float* b1b    = (const float*)d_in[7];
  const float* w2a    = (const float*)d_in[8];
  const float* b2a    = (const float*)d_in[9];
  const float* g2     = (const float*)d_in[10];
  const float* beta2  = (const float*)d_in[11];
  const float* w2b    = (const float*)d_in[12];
  const float* b2b    = (const float*)d_in[13];
  float* out = (float*)d_out;
  char* ws = (char*)d_ws;

  if (ws_size < WS_NEED){
    k_sig<<<1, 256, 0, stream>>>(out, 10000.f + (float)(ws_size >> 20));
    return;
  }

  float*     sums   = (float*)(ws + WS_SUMS);
  u16*       a1     = (u16*)(ws + WS_A1);
  u16*       h      = (u16*)(ws + WS_H);
  unsigned*  pool_u = (unsigned*)(ws + WS_POOLU);
  u16*       poolbf = (u16*)(ws + WS_PBF);
  unsigned*  out_u  = (unsigned*)(ws + WS_OUTU);
  u16*       wt1    = (u16*)(ws + WS_WT1);
  u16*       wt2a   = (u16*)(ws + WS_WT2A);
  u16*       wt2b   = (u16*)(ws + WS_WT2B);
  float*     prepf  = (float*)(ws + WS_PREP);
  int*       offs   = (int*)(ws + WS_OFFS);
  int*       cursor = (int*)(ws + WS_CUR);
  int*       sortpos= (int*)(ws + WS_SPOS);
  int*       glab   = (int*)(ws + WS_GLAB);

  float* cent_out = out + OFF_CENT;
  float* out_seg  = out + OFF_OUT;
  float* pi_out   = out + OFF_PI;
  float* lab_out  = out + OFF_LAB;

  k_init<<<4096, 256, 0, stream>>>(sums, cursor, pool_u, out_u);
  k_wt<<<(128*256+255)/256, 256, 0, stream>>>(w1b, wt1, 128, 256);
  k_wt<<<(512*512+255)/256, 256, 0, stream>>>(w2a, wt2a, 512, 512);
  k_wt<<<(512*256+255)/256, 256, 0, stream>>>(w2b, wt2b, 512, 256);
  k_points<<<NP/256, 256, 0, stream>>>(xyz, labels, sums, lab_out);
  k_cent<<<(NB_*NG+255)/256, 256, 0, stream>>>(sums, cent_out);
  k_scan<<<NB_, 256, 0, stream>>>(sums, offs);
  k_scatter<<<NP/256, 256, 0, stream>>>(labels, offs, cursor, sortpos, glab);
  k_mlp1<<<NP/4, 256, 0, stream>>>(xyz, labels, sortpos, cent_out,
                                   w1a, b1a, g1, beta1, a1, pi_out);
  // GEMM1: h = a1 @ w1b + b1b (sorted rows); bf16 store + dedup pool atomicMax
  mgemm<0><<<(NP/128)*(256/128), 256, 0, stream>>>(
      a1, 128, 128, wt1, 128, 0, b1b, glab,
      h, (float*)nullptr, 256, 256, pool_u);
  k_poolfin<<<4096, 256, 0, stream>>>(pool_u, poolbf);
  // prep = poolbf @ w2a[0:256,:] + b2a : [B*G, 512] f32
  mgemm<3><<<(NB_*NG/128)*(512/128), 256, 0, stream>>>(
      poolbf, 256, 256, wt2a, 512, 0, b2a, (const int*)nullptr,
      (u16*)nullptr, prepf, 512, 512, (unsigned*)nullptr);
  // fused: GEMM2a' + LN + GEMM2b + segmax (sorted rows)
  fused2<<<NP/64, 512, 0, stream>>>(h, wt2a, wt2b, prepf, b2b, g2, beta2, glab, out_u);
  k_outfin<<<4096, 256, 0, stream>>>(out_u, out_seg);
}

// Round 7
// 345.479 us; speedup vs baseline: 1.3117x; 1.3117x over previous
//
#include <hip/hip_runtime.h>
#include <hip/hip_bf16.h>

// Problem constants
#define NB_  16
#define NPTS 8192
#define NG   256
#define NP   (NB_*NPTS)   // 131072 points
#define NBLK (NP/64)      // 2048 fused2 blocks

// Output segment offsets (floats)
#define OFF_CENT 0
#define OFF_OUT  12288
#define OFF_PI   1060864
#define OFF_LAB  1454080

typedef unsigned short u16;
typedef __attribute__((ext_vector_type(8))) short bf16x8;
typedef __attribute__((ext_vector_type(4))) float f32x4;

// Workspace layout (bytes)
static constexpr size_t WS_SUMS  = 0;                                // B*G*4 f32 = 64KB
static constexpr size_t WS_A1    = 65536;                            // P*128 bf16 = 32MB (sorted)
static constexpr size_t WS_H     = WS_A1   + (size_t)NP*128*2;       // P*256 bf16 = 64MB (sorted)
static constexpr size_t WS_PBF   = WS_H    + (size_t)NP*256*2;       // B*G*256 bf16 = 2MB
static constexpr size_t WS_WT1   = WS_PBF  + (size_t)NB_*NG*256*2;   // 256x128 bf16
static constexpr size_t WS_WT2A  = WS_WT1  + (size_t)256*128*2;      // 512x512 bf16
static constexpr size_t WS_WT2B  = WS_WT2A + (size_t)512*512*2;      // 256x512 bf16
static constexpr size_t WS_PREP  = WS_WT2B + (size_t)256*512*2;      // 4096x512 f32 = 8MB
static constexpr size_t WS_OFFS  = WS_PREP + (size_t)NB_*NG*512*4;   // 4096 i32
static constexpr size_t WS_CNT   = WS_OFFS + (size_t)NB_*NG*4;       // 4096 i32
static constexpr size_t WS_CUR   = WS_CNT  + (size_t)NB_*NG*4;       // 4096 i32
static constexpr size_t WS_SPOS  = WS_CUR  + (size_t)NB_*NG*4;       // NP i32
static constexpr size_t WS_GLAB  = WS_SPOS + (size_t)NP*4;           // NP i32
static constexpr size_t WS_PF    = WS_GLAB + (size_t)NP*4;           // NBLK*256 f32 = 2MB
static constexpr size_t WS_PL    = WS_PF   + (size_t)NBLK*256*4;     // NBLK*256 f32 = 2MB
static constexpr size_t WS_DST   = WS_PL   + (size_t)NBLK*256*4;     // B*G*256 f32 = 4MB
static constexpr size_t WS_NEED  = WS_DST  + (size_t)NB_*NG*256*4;   // ~115 MB

__device__ __forceinline__ u16 f2bf_bits(float f){
  __hip_bfloat16 h = __float2bfloat16(f);
  union { __hip_bfloat16 h; u16 s; } u; u.h = h; return u.s;
}
__device__ __forceinline__ float bf_bits2f(u16 s){
  return __uint_as_float(((unsigned)s) << 16);
}

// async global->LDS, 16B per lane. LDS dest must be wave-uniform base (lane*16 added by HW).
__device__ __forceinline__ void gload16(const void* g, void* l){
  __builtin_amdgcn_global_load_lds((const __attribute__((address_space(1))) void*)g,
                                   (__attribute__((address_space(3))) void*)l, 16, 0, 0);
}

// ---------------- init: zero sums + cursor ----------------
__global__ void k_init(float* __restrict__ sums, int* __restrict__ cursor){
  int i = blockIdx.x*blockDim.x + threadIdx.x;
  if (i < NB_*NG*4) sums[i] = 0.f;
  if (i < NB_*NG) cursor[i] = 0;
}

// ---------------- weight transpose+bf16: dst[n*K+k] = bf16(src[k*N+n]) ----------------
__global__ void k_wt(const float* __restrict__ src, u16* __restrict__ dst, int K, int N){
  int i = blockIdx.x*blockDim.x + threadIdx.x;
  if (i >= K*N) return;
  int n = i / K, k = i - n*K;
  dst[i] = f2bf_bits(src[(size_t)k*N + n]);
}

// ---------------- per-point pass 1: segment sums + labels-as-float ----------------
__global__ void k_points(const float* __restrict__ xyz, const int* __restrict__ labels,
                         float* __restrict__ sums, float* __restrict__ outLab){
  int p = blockIdx.x*blockDim.x + threadIdx.x;
  if (p >= NP) return;
  int b = p / NPTS;
  int g = labels[p];
  float x = xyz[p*3+0], y = xyz[p*3+1], z = xyz[p*3+2];
  float* s = sums + (size_t)(b*NG + g)*4;
  atomicAdd(s+0, x); atomicAdd(s+1, y); atomicAdd(s+2, z); atomicAdd(s+3, 1.f);
  outLab[p] = (float)g;
}

// ---------------- centroids ----------------
__global__ void k_cent(const float* __restrict__ sums, float* __restrict__ cent_out){
  int i = blockIdx.x*blockDim.x + threadIdx.x;   // b*G+g
  if (i >= NB_*NG) return;
  const float* s = sums + (size_t)i*4;
  float c = fmaxf(s[3], 1.f);
  cent_out[i*3+0] = s[0]/c;
  cent_out[i*3+1] = s[1]/c;
  cent_out[i*3+2] = s[2]/c;
}

// ---------------- exclusive scan of counts per batch -> offs (absolute), counts ----------------
__global__ void k_scan(const float* __restrict__ sums, int* __restrict__ offs,
                       int* __restrict__ counts){
  __shared__ int sc[256];
  int b = blockIdx.x, g = threadIdx.x;
  int c = (int)(sums[(size_t)(b*NG+g)*4+3] + 0.5f);
  sc[g] = c;
  __syncthreads();
  for (int d = 1; d < 256; d <<= 1){
    int t = (g >= d) ? sc[g-d] : 0;
    __syncthreads();
    sc[g] += t;
    __syncthreads();
  }
  offs[b*NG+g] = b*NPTS + sc[g] - c;   // exclusive, absolute row index
  counts[b*NG+g] = c;
}

// ---------------- scatter: sorted position per point; sorted labels ----------------
__global__ void k_scatter(const int* __restrict__ labels, const int* __restrict__ offs,
                          int* __restrict__ cursor, int* __restrict__ sortpos,
                          int* __restrict__ glab){
  int p = blockIdx.x*blockDim.x + threadIdx.x;
  if (p >= NP) return;
  int b = p / NPTS, g = labels[p];
  int pos = offs[b*NG+g] + atomicAdd(&cursor[b*NG+g], 1);
  sortpos[p] = pos;
  glab[pos] = g;
}

// ---------------- MLP1 front: rel@w1a+b1a -> LN -> ReLU -> a1 (bf16, SORTED), also p_i ----
__global__ __launch_bounds__(256) void k_mlp1(
    const float* __restrict__ xyz, const int* __restrict__ labels,
    const int* __restrict__ sortpos, const float* __restrict__ cent,
    const float* __restrict__ w1a, const float* __restrict__ b1a,
    const float* __restrict__ g1, const float* __restrict__ beta1,
    u16* __restrict__ a1, float* __restrict__ pi_out)
{
  int wave = (int)((blockIdx.x*blockDim.x + threadIdx.x) >> 6);
  int lane = threadIdx.x & 63;
  int p = wave;
  if (p >= NP) return;
  int b = p / NPTS;
  int g = labels[p];
  const float* cb = cent + (size_t)(b*NG+g)*3;
  float c0 = cb[0], c1 = cb[1], c2 = cb[2];
  float r0 = xyz[p*3+0]-c0, r1 = xyz[p*3+1]-c1, r2 = xyz[p*3+2]-c2;
  if (lane < 3) pi_out[(size_t)p*3+lane] = (lane==0?c0:(lane==1?c1:c2));
  int j = lane*2;
  float2 wa0 = *(const float2*)(w1a + 0*128 + j);
  float2 wa1 = *(const float2*)(w1a + 1*128 + j);
  float2 wa2 = *(const float2*)(w1a + 2*128 + j);
  float2 bb  = *(const float2*)(b1a + j);
  float t0 = bb.x + r0*wa0.x + r1*wa1.x + r2*wa2.x;
  float t1 = bb.y + r0*wa0.y + r1*wa1.y + r2*wa2.y;
  float s = t0+t1, sq = t0*t0 + t1*t1;
  #pragma unroll
  for (int m = 32; m; m >>= 1){ s += __shfl_xor(s, m); sq += __shfl_xor(sq, m); }
  float mu  = s * (1.f/128.f);
  float var = sq * (1.f/128.f) - mu*mu;
  float inv = rsqrtf(var + 1e-5f);
  float2 gg = *(const float2*)(g1 + j), be = *(const float2*)(beta1 + j);
  float a0 = fmaxf((t0-mu)*inv*gg.x + be.x, 0.f);
  float a1v = fmaxf((t1-mu)*inv*gg.y + be.y, 0.f);
  unsigned pk = ((unsigned)f2bf_bits(a1v) << 16) | f2bf_bits(a0);
  int sp = sortpos[p];
  *reinterpret_cast<unsigned*>(a1 + (size_t)sp*128 + j) = pk;
}

// ---------------- MFMA bf16 GEMM (generic): C[M][Nc] = A@B + bias ----------------
// EPI 1: bf16 store;  EPI 3: f32 store (Cf).  No atomics.
template<int EPI>
__global__ __launch_bounds__(256)
void mgemm(const u16* __restrict__ A, int lda, int K,
           const u16* __restrict__ BT, int ldb, int kofs,
           const float* __restrict__ bias,
           u16* __restrict__ Cst, float* __restrict__ Cf, int ldc, int Nc)
{
  __shared__ alignas(16) u16 As[128*32];
  __shared__ alignas(16) u16 Bs[128*32];
  int NBk = Nc >> 7;
  int bm = blockIdx.x / NBk, bn = blockIdx.x % NBk;
  int m0 = bm << 7, n0 = bn << 7;
  int tid = threadIdx.x;
  int lane = tid & 63, w = tid >> 6;
  int wr = w >> 1, wc = w & 1;
  int l15 = lane & 15, l4 = lane >> 4;
  int r0 = tid >> 2;
  int ks = (tid & 3) << 3;
  u16* asd0 = As + (size_t)(w*64)*8;
  u16* asd1 = As + (size_t)(256 + w*64)*8;
  u16* bsd0 = Bs + (size_t)(w*64)*8;
  u16* bsd1 = Bs + (size_t)(256 + w*64)*8;
  f32x4 acc[4][4];
  #pragma unroll
  for (int i = 0; i < 4; ++i)
    #pragma unroll
    for (int jj = 0; jj < 4; ++jj)
      #pragma unroll
      for (int e = 0; e < 4; ++e) acc[i][jj][e] = 0.f;

  for (int k0 = 0; k0 < K; k0 += 32){
    gload16(A + (size_t)(m0 + r0)*lda + k0 + ks, asd0);
    gload16(A + (size_t)(m0 + r0 + 64)*lda + k0 + ks, asd1);
    gload16(BT + (size_t)(n0 + r0)*ldb + kofs + k0 + ks, bsd0);
    gload16(BT + (size_t)(n0 + r0 + 64)*ldb + kofs + k0 + ks, bsd1);
    __syncthreads();
    bf16x8 af[4], bfr[4];
    #pragma unroll
    for (int i = 0; i < 4; ++i){
      af[i]  = *(const bf16x8*)&As[(size_t)(wr*64 + i*16 + l15)*32 + l4*8];
      bfr[i] = *(const bf16x8*)&Bs[(size_t)(wc*64 + i*16 + l15)*32 + l4*8];
    }
    #pragma unroll
    for (int i = 0; i < 4; ++i)
      #pragma unroll
      for (int jj = 0; jj < 4; ++jj)
        acc[i][jj] = __builtin_amdgcn_mfma_f32_16x16x32_bf16(af[i], bfr[jj], acc[i][jj], 0, 0, 0);
    __syncthreads();
  }

  float bi[4];
  #pragma unroll
  for (int jj = 0; jj < 4; ++jj) bi[jj] = bias[n0 + wc*64 + jj*16 + l15];
  #pragma unroll
  for (int i = 0; i < 4; ++i){
    #pragma unroll
    for (int r = 0; r < 4; ++r){
      int m = m0 + wr*64 + i*16 + l4*4 + r;
      #pragma unroll
      for (int jj = 0; jj < 4; ++jj){
        int n = n0 + wc*64 + jj*16 + l15;
        float v = acc[i][jj][r] + bi[jj];
        if (EPI == 1) Cst[(size_t)m*ldc + n] = f2bf_bits(v);
        if (EPI == 3) Cf[(size_t)m*ldc + n] = v;
      }
    }
  }
}

// ---------------- pool: per-group streaming max over sorted h -> poolbf ----------------
__global__ __launch_bounds__(256) void k_pool(const u16* __restrict__ h,
                                              const int* __restrict__ offs,
                                              const int* __restrict__ counts,
                                              u16* __restrict__ poolbf){
  int bg = blockIdx.x, c = threadIdx.x;
  int cnt = counts[bg];
  if (cnt == 0){ poolbf[(size_t)bg*256 + c] = 0; return; }   // bf16 +0
  int off = offs[bg];
  float mx = bf_bits2f(h[(size_t)off*256 + c]);
  for (int r = 1; r < cnt; ++r)
    mx = fmaxf(mx, bf_bits2f(h[(size_t)(off+r)*256 + c]));
  poolbf[(size_t)bg*256 + c] = f2bf_bits(mx);
}

// ---------------- fused: u = h@W2a_bot + prep[gather] ; LN+ReLU ; v = u@w2b ; seg-partials ----
// Rows in sorted-by-label order. 512 threads = 8 waves; M-tile 64; LDS 80KB -> 2 blocks/CU.
// Epilogue: NO atomics. vbuf[64][256] in LDS; per-channel walk over sorted labels emits:
//  first seg (starts at block-row 0) -> pf[blk]; last seg (ends row 63) -> pl[blk];
//  interior segs (sole owner) -> dstage[bg].
__global__ __launch_bounds__(512, 4)
void fused2(const u16* __restrict__ h, const u16* __restrict__ wt2a,
            const u16* __restrict__ wt2b, const float* __restrict__ prepf,
            const float* __restrict__ b2b, const float* __restrict__ g2,
            const float* __restrict__ beta2, const int* __restrict__ glab,
            float* __restrict__ pf, float* __restrict__ pl, float* __restrict__ dstage)
{
  __shared__ alignas(16) char smem[81920];
  float* ssum = (float*)(smem + 65536);        // [64] f32 (aliases phase-2 B tile)
  float* ssq  = (float*)(smem + 65536 + 256);  // [64] f32
  int tid = threadIdx.x;
  int w = tid >> 6, lane = tid & 63;
  int l15 = lane & 15, l4 = lane >> 4;
  int m0 = blockIdx.x << 6;
  int srow = lane >> 2, skseg = (lane & 3) << 3;
  if (tid < 64){ ssum[tid] = 0.f; ssq[tid] = 0.f; }

  f32x4 acc[4][4];
  #pragma unroll
  for (int i = 0; i < 4; ++i)
    #pragma unroll
    for (int j = 0; j < 4; ++j)
      #pragma unroll
      for (int e = 0; e < 4; ++e) acc[i][j][e] = 0.f;

  // ---- phase 1: acc = h_tile @ W2a_bot ----
  for (int k0 = 0; k0 < 256; k0 += 32){
    if (w < 4)
      gload16(h + (size_t)(m0 + (w<<4) + srow)*256 + k0 + skseg, smem + (w<<10));
    #pragma unroll
    for (int q = 0; q < 4; ++q){
      int n = (w<<6) + (q<<4) + srow;
      gload16(wt2a + (size_t)n*512 + 256 + k0 + skseg,
              smem + 4096 + (((w<<6) + (q<<4)) << 6));
    }
    __syncthreads();
    bf16x8 af[4], bf[4];
    #pragma unroll
    for (int i = 0; i < 4; ++i)
      af[i] = *(const bf16x8*)(smem + ((((i<<4)+l15)) << 6) + (l4<<4));
    #pragma unroll
    for (int j = 0; j < 4; ++j)
      bf[j] = *(const bf16x8*)(smem + 4096 + (((w<<6)+(j<<4)+l15) << 6) + (l4<<4));
    #pragma unroll
    for (int i = 0; i < 4; ++i)
      #pragma unroll
      for (int j = 0; j < 4; ++j)
        acc[i][j] = __builtin_amdgcn_mfma_f32_16x16x32_bf16(af[i], bf[j], acc[i][j], 0, 0, 0);
    __syncthreads();
  }

  // ---- phase 1.5: + prep gather, LayerNorm + ReLU, write u to LDS (swizzled bf16) ----
  int gb = (m0 / NPTS) * NG;
  int grp[4][4];
  #pragma unroll
  for (int i = 0; i < 4; ++i)
    #pragma unroll
    for (int r = 0; r < 4; ++r)
      grp[i][r] = gb + glab[m0 + (i<<4) + (l4<<2) + r];
  #pragma unroll
  for (int i = 0; i < 4; ++i)
    #pragma unroll
    for (int j = 0; j < 4; ++j){
      int n = (w<<6) + (j<<4) + l15;
      #pragma unroll
      for (int r = 0; r < 4; ++r)
        acc[i][j][r] += prepf[((size_t)grp[i][r] << 9) + n];
    }
  #pragma unroll
  for (int i = 0; i < 4; ++i)
    #pragma unroll
    for (int r = 0; r < 4; ++r){
      float s = 0.f, q = 0.f;
      #pragma unroll
      for (int j = 0; j < 4; ++j){ float v = acc[i][j][r]; s += v; q += v*v; }
      #pragma unroll
      for (int mk = 1; mk < 16; mk <<= 1){ s += __shfl_xor(s, mk); q += __shfl_xor(q, mk); }
      if (l15 == 0){
        int row = (i<<4) + (l4<<2) + r;
        atomicAdd(&ssum[row], s);
        atomicAdd(&ssq[row], q);
      }
    }
  __syncthreads();
  if (tid < 64){
    float mu = ssum[tid] * (1.f/512.f);
    float var = ssq[tid] * (1.f/512.f) - mu*mu;
    ssum[tid] = mu;
    ssq[tid] = rsqrtf(var + 1e-5f);
  }
  __syncthreads();
  float gcol[4], bcol[4];
  #pragma unroll
  for (int j = 0; j < 4; ++j){
    int n = (w<<6) + (j<<4) + l15;
    gcol[j] = g2[n]; bcol[j] = beta2[n];
  }
  #pragma unroll
  for (int i = 0; i < 4; ++i)
    #pragma unroll
    for (int r = 0; r < 4; ++r){
      int row = (i<<4) + (l4<<2) + r;
      float mu = ssum[row], inv = ssq[row];
      #pragma unroll
      for (int j = 0; j < 4; ++j){
        int n = (w<<6) + (j<<4) + l15;
        float v = fmaxf((acc[i][j][r] - mu)*inv*gcol[j] + bcol[j], 0.f);
        int byo = (row << 10) + (n << 1);
        byo ^= (row & 7) << 4;
        *(u16*)(smem + byo) = f2bf_bits(v);
      }
    }
  __syncthreads();

  // ---- phase 2: v = u_lds @ w2b ----
  f32x4 acc2[4][2];
  #pragma unroll
  for (int i = 0; i < 4; ++i)
    #pragma unroll
    for (int j = 0; j < 2; ++j)
      #pragma unroll
      for (int e = 0; e < 4; ++e) acc2[i][j][e] = 0.f;

  for (int k0 = 0; k0 < 512; k0 += 32){
    #pragma unroll
    for (int q = 0; q < 2; ++q){
      int n = (w<<5) + (q<<4) + srow;
      gload16(wt2b + (size_t)n*512 + k0 + skseg,
              smem + 65536 + (((w<<5) + (q<<4)) << 6));
    }
    __syncthreads();
    bf16x8 af2[4], bf2[2];
    #pragma unroll
    for (int i = 0; i < 4; ++i){
      int row = (i<<4) + l15;
      int byo = (row << 10) + ((k0 + (l4<<3)) << 1);
      byo ^= (row & 7) << 4;
      af2[i] = *(const bf16x8*)(smem + byo);
    }
    #pragma unroll
    for (int j = 0; j < 2; ++j)
      bf2[j] = *(const bf16x8*)(smem + 65536 + (((w<<5)+(j<<4)+l15) << 6) + (l4<<4));
    #pragma unroll
    for (int i = 0; i < 4; ++i)
      #pragma unroll
      for (int j = 0; j < 2; ++j)
        acc2[i][j] = __builtin_amdgcn_mfma_f32_16x16x32_bf16(af2[i], bf2[j], acc2[i][j], 0, 0, 0);
    __syncthreads();
  }

  // ---- epilogue: v -> vbuf (aliases dead u region), per-channel segment walk ----
  float bb0 = b2b[(w<<5) + l15], bb1 = b2b[(w<<5) + 16 + l15];
  float* vbuf = (float*)smem;                  // [64][256] f32
  int* glab_s = (int*)(smem + 65536);          // [64] (phase-2 B tile dead now)
  #pragma unroll
  for (int i = 0; i < 4; ++i)
    #pragma unroll
    for (int j = 0; j < 2; ++j){
      int n = (w<<5) + (j<<4) + l15;
      float bbj = j ? bb1 : bb0;
      #pragma unroll
      for (int r = 0; r < 4; ++r){
        int row = (i<<4) + (l4<<2) + r;
        vbuf[row*256 + n] = acc2[i][j][r] + bbj;
      }
    }
  if (tid < 64) glab_s[tid] = glab[m0 + tid];
  __syncthreads();
  if (tid < 256){
    int c = tid;
    size_t blk = blockIdx.x;
    int curg = glab_s[0];
    float mx = vbuf[c];
    bool from0 = true;
    for (int r = 1; r < 64; ++r){
      int g = glab_s[r];
      float v = vbuf[r*256 + c];
      if (g != curg){
        if (from0) pf[blk*256 + c] = mx;
        else       dstage[((size_t)(gb + curg))*256 + c] = mx;
        curg = g; mx = v; from0 = false;
      } else mx = fmaxf(mx, v);
    }
    if (from0) pf[blk*256 + c] = mx;
    else       pl[blk*256 + c] = mx;
  }
}

// ---------------- combine: out[bg] = max over block partials (deterministic) ----------------
__global__ __launch_bounds__(256) void k_combine(const int* __restrict__ offs,
                                                 const int* __restrict__ counts,
                                                 const float* __restrict__ pf,
                                                 const float* __restrict__ pl,
                                                 const float* __restrict__ dstage,
                                                 float* __restrict__ outp){
  int bg = blockIdx.x, c = threadIdx.x;
  int cnt = counts[bg];
  if (cnt == 0){ outp[(size_t)bg*256 + c] = 0.f; return; }
  int off = offs[bg], end = off + cnt;
  int B0 = off >> 6, B1 = (end - 1) >> 6;
  float v;
  if (B0 == B1){
    if ((off & 63) == 0)      v = pf[(size_t)B0*256 + c];
    else if ((end & 63) == 0) v = pl[(size_t)B0*256 + c];
    else                      v = dstage[(size_t)bg*256 + c];
  } else {
    v = ((off & 63) == 0) ? pf[(size_t)B0*256 + c] : pl[(size_t)B0*256 + c];
    for (int k = B0 + 1; k <= B1; ++k)
      v = fmaxf(v, pf[(size_t)k*256 + c]);
  }
  outp[(size_t)bg*256 + c] = v;
}

// ---------------- ws-too-small signal ----------------
__global__ void k_sig(float* __restrict__ out, float val){
  int i = blockIdx.x*blockDim.x + threadIdx.x;
  if (i < 256) out[i] = val;
}

extern "C" void kernel_launch(void* const* d_in, const int* in_sizes, int n_in,
                              void* d_out, int out_size, void* d_ws, size_t ws_size,
                              hipStream_t stream) {
  const float* xyz    = (const float*)d_in[0];
  const int*   labels = (const int*)  d_in[1];
  const float* w1a    = (const float*)d_in[2];
  const float* b1a    = (const float*)d_in[3];
  const float* g1     = (const float*)d_in[4];
  const float* beta1  = (const float*)d_in[5];
  const float* w1b    = (const float*)d_in[6];
  const float* b1b    = (const float*)d_in[7];
  const float* w2a    = (const float*)d_in[8];
  const float* b2a    = (const float*)d_in[9];
  const float* g2     = (const float*)d_in[10];
  const float* beta2  = (const float*)d_in[11];
  const float* w2b    = (const float*)d_in[12];
  const float* b2b    = (const float*)d_in[13];
  float* out = (float*)d_out;
  char* ws = (char*)d_ws;

  if (ws_size < WS_NEED){
    k_sig<<<1, 256, 0, stream>>>(out, 10000.f + (float)(ws_size >> 20));
    return;
  }

  float*     sums   = (float*)(ws + WS_SUMS);
  u16*       a1     = (u16*)(ws + WS_A1);
  u16*       h      = (u16*)(ws + WS_H);
  u16*       poolbf = (u16*)(ws + WS_PBF);
  u16*       wt1    = (u16*)(ws + WS_WT1);
  u16*       wt2a   = (u16*)(ws + WS_WT2A);
  u16*       wt2b   = (u16*)(ws + WS_WT2B);
  float*     prepf  = (float*)(ws + WS_PREP);
  int*       offs   = (int*)(ws + WS_OFFS);
  int*       counts = (int*)(ws + WS_CNT);
  int*       cursor = (int*)(ws + WS_CUR);
  int*       sortpos= (int*)(ws + WS_SPOS);
  int*       glab   = (int*)(ws + WS_GLAB);
  float*     pf     = (float*)(ws + WS_PF);
  float*     pl     = (float*)(ws + WS_PL);
  float*     dstage = (float*)(ws + WS_DST);

  float* cent_out = out + OFF_CENT;
  float* out_seg  = out + OFF_OUT;
  float* pi_out   = out + OFF_PI;
  float* lab_out  = out + OFF_LAB;

  k_init<<<64, 256, 0, stream>>>(sums, cursor);
  k_wt<<<(128*256+255)/256, 256, 0, stream>>>(w1b, wt1, 128, 256);
  k_wt<<<(512*512+255)/256, 256, 0, stream>>>(w2a, wt2a, 512, 512);
  k_wt<<<(512*256+255)/256, 256, 0, stream>>>(w2b, wt2b, 512, 256);
  k_points<<<NP/256, 256, 0, stream>>>(xyz, labels, sums, lab_out);
  k_cent<<<(NB_*NG+255)/256, 256, 0, stream>>>(sums, cent_out);
  k_scan<<<NB_, 256, 0, stream>>>(sums, offs, counts);
  k_scatter<<<NP/256, 256, 0, stream>>>(labels, offs, cursor, sortpos, glab);
  k_mlp1<<<NP/4, 256, 0, stream>>>(xyz, labels, sortpos, cent_out,
                                   w1a, b1a, g1, beta1, a1, pi_out);
  // GEMM1: h = a1 @ w1b + b1b (sorted rows); bf16 store, no atomics
  mgemm<1><<<(NP/128)*(256/128), 256, 0, stream>>>(
      a1, 128, 128, wt1, 128, 0, b1b, h, (float*)nullptr, 256, 256);
  // pool: per-group max over sorted h -> poolbf
  k_pool<<<NB_*NG, 256, 0, stream>>>(h, offs, counts, poolbf);
  // prep = poolbf @ w2a[0:256,:] + b2a : [B*G, 512] f32
  mgemm<3><<<(NB_*NG/128)*(512/128), 256, 0, stream>>>(
      poolbf, 256, 256, wt2a, 512, 0, b2a, (u16*)nullptr, prepf, 512, 512);
  // fused: GEMM2a' + LN + GEMM2b -> block partial maxes (no atomics)
  fused2<<<NBLK, 512, 0, stream>>>(h, wt2a, wt2b, prepf, b2b, g2, beta2, glab,
                                   pf, pl, dstage);
  // combine partials -> out
  k_combine<<<NB_*NG, 256, 0, stream>>>(offs, counts, pf, pl, dstage, out_seg);
}